// Round 17
// baseline (199.136 us; speedup 1.0000x reference)
//
#include <hip/hip_runtime.h>

typedef short bf16x8 __attribute__((ext_vector_type(8)));
typedef float f32x4 __attribute__((ext_vector_type(4)));
typedef unsigned short u16;
typedef u16 ushort8v __attribute__((ext_vector_type(8)));

// ---- constants ----
#define VOCAB 100000
#define EMB 300
#define SEQ 40
#define BATCH 8192
#define COUT 210
#define NBLK 5
#define KPOOL 38
#define DH 35
#define NCLS 35
#define PCOL 320            // padded w2v row: 300 real + 20 zero (16B-aligned rows)
#define NUSE 192            // only channels 0..189 feed the pool
#define BM 80               // 2 batches per block
#define EROWS 84            // 2 x 42 padded rows
#define GSLOT 28            // resident granule slots: 28*84*16 = 37,632 B -> 4 blocks/CU
                            // (r16: 40 slots = 53,760 B -> 3 blocks/CU; waves/CU 12 -> 16)
#define ASTR 197            // act row stride (odd; harmless)
#define NGR 120

__device__ __forceinline__ u16 f2bf(float f) {
  unsigned u = __float_as_uint(f);
  unsigned r = 0x7FFFu + ((u >> 16) & 1u);
  return (u16)((u + r) >> 16);
}

__device__ __forceinline__ void gload_lds16(void* lds, const void* g) {
  __builtin_amdgcn_global_load_lds(
      (const __attribute__((address_space(1))) void*)g,
      (__attribute__((address_space(3))) void*)lds, 16, 0, 0);
}

// ---- kernel 1: w2v f32 [VOCAB][300] -> W bf16 [VOCAB+1][320]; row VOCAB = zeros ----
__global__ __launch_bounds__(256) void k_prepW(const float* __restrict__ w2v,
                                               u16* __restrict__ W) {
  int id = blockIdx.x * 256 + threadIdx.x;          // (VOCAB+1)*40 chunks of 8
  if (id >= (VOCAB + 1) * 40) return;
  int v = id / 40, e8 = id - v * 40;
  int e = e8 * 8;
  float vals[8] = {0.f, 0.f, 0.f, 0.f, 0.f, 0.f, 0.f, 0.f};
  if (v < VOCAB) {
    const float* src = w2v + (size_t)v * EMB + e;
    if (e <= 292) {
      float4 f0 = *(const float4*)src;
      float4 f1 = *(const float4*)(src + 4);
      vals[0] = f0.x; vals[1] = f0.y; vals[2] = f0.z; vals[3] = f0.w;
      vals[4] = f1.x; vals[5] = f1.y; vals[6] = f1.z; vals[7] = f1.w;
    } else if (e == 296) {
      float4 f0 = *(const float4*)src;               // 296..299
      vals[0] = f0.x; vals[1] = f0.y; vals[2] = f0.z; vals[3] = f0.w;
    }
  }
  ushort8v o;
#pragma unroll
  for (int j = 0; j < 8; ++j) o[j] = f2bf(vals[j]);
  *(ushort8v*)(W + (size_t)v * PCOL + e) = o;
}

// ---- kernel 2: conv_w [3][300][210] -> Btn bf16 [120 gran][192 col][8] (zero padded) ----
__global__ __launch_bounds__(256) void k_prepB(const float* __restrict__ convw,
                                               u16* __restrict__ Btn) {
  int id = blockIdx.x * 256 + threadIdx.x;          // 120*192 = 23040
  if (id >= NGR * NUSE) return;
  int gg = id / NUSE, col = id - gg * NUSE;
  ushort8v o;
#pragma unroll
  for (int j = 0; j < 8; ++j) {
    int k = gg * 8 + j;
    int kh = (k >= 640) ? 2 : (k >= 320 ? 1 : 0);
    int e = k - kh * PCOL;
    float v = (e < EMB) ? convw[(kh * EMB + e) * COUT + col] : 0.f;
    o[j] = f2bf(v);
  }
  *(ushort8v*)(Btn + (size_t)id * 8) = o;
}

// ---- kernel 3: fused gather + conv (3 shifted K=320 sub-GEMMs) + bias/relu/pool ----
// r16 structure with a 28+12 granule split: stage 28 granules (37,632 B -> 4 blocks/CU,
// 16 waves/CU vs r16's 12), run 21 barrier-free steps (kh 0..2 x kq 0..6), ONE mid-kernel
// restage of granules 28..39 into slots 0..11, then 9 more steps (kq 7..9). The restage
// of one block hides under 3 siblings' compute. Everything else identical to r16.
__global__ __launch_bounds__(256) void k_conv_gemm(const u16* __restrict__ Wb,
                                                   const u16* __restrict__ Btn,
                                                   const int* __restrict__ x,
                                                   const float* __restrict__ convb,
                                                   float* __restrict__ maxc) {
  __shared__ __align__(16) char smem[GSLOT * EROWS * 16];   // 37,632 B; epilogue aliases act
  float* act = (float*)smem;                                 // [16][197] = 12,608 B

  const int tid = threadIdx.x;
  const int lane = tid & 63;
  const int wc = tid >> 6;                          // wave = N-slot 0..3
  const int l15 = lane & 15, l4 = lane >> 4;
  const int b0 = blockIdx.x * 2;

  // ---- per-lane A row indices (fold batch-boundary pad jump) ----
  const int rA0 = l15;
  const int rA1 = 16 + l15;
  const int rA2 = 32 + l15 + ((l15 >= 8) ? 2 : 0);  // straddles batch boundary
  const int rA3 = 50 + l15;
  const int rA4 = 66 + l15;

  // ---- B setup: frag (granule 4T+l4, col wc*48+fn*16+l15); tile T at +T*6144 ----
  const u16* pbB = Btn + (size_t)((l4 * NUSE) + wc * 48 + l15) * 8;

  f32x4 acc[5][3];
  const f32x4 zero = {0.f, 0.f, 0.f, 0.f};
#pragma unroll
  for (int i = 0; i < 5; ++i)
#pragma unroll
    for (int j = 0; j < 3; ++j) acc[i][j] = zero;

  bf16x8 aR[2][5];                                  // ping-pong A sets
  bf16x8 bs[3][3];                                  // 3 rotating B sets

#define LOADB(SI, T)                                                           \
  {                                                                            \
    const u16* p_ = pbB + (size_t)(T) * 6144;                                  \
    bs[SI][0] = *(const bf16x8*)(p_);                                          \
    bs[SI][1] = *(const bf16x8*)(p_ + 128);                                    \
    bs[SI][2] = *(const bf16x8*)(p_ + 256);                                    \
  }

  // A frags: local slot quad QD (granules 4*QD+l4), row shift KH
#define LOADA(SL, QD, KH)                                                      \
  {                                                                            \
    const char* kb_ = smem + (((QD) * 4 + l4) * EROWS + (KH)) * 16;            \
    aR[SL][0] = *(const bf16x8*)(kb_ + rA0 * 16);                              \
    aR[SL][1] = *(const bf16x8*)(kb_ + rA1 * 16);                              \
    aR[SL][2] = *(const bf16x8*)(kb_ + rA2 * 16);                              \
    aR[SL][3] = *(const bf16x8*)(kb_ + rA3 * 16);                              \
    aR[SL][4] = *(const bf16x8*)(kb_ + rA4 * 16);                              \
  }

#define MFMAS(SL, SB)                                                          \
  __builtin_amdgcn_s_setprio(1);                                               \
  _Pragma("unroll")                                                            \
  for (int fn = 0; fn < 3; ++fn) {                                             \
    acc[0][fn] = __builtin_amdgcn_mfma_f32_16x16x32_bf16(aR[SL][0], bs[SB][fn], acc[0][fn], 0, 0, 0); \
    acc[1][fn] = __builtin_amdgcn_mfma_f32_16x16x32_bf16(aR[SL][1], bs[SB][fn], acc[1][fn], 0, 0, 0); \
    acc[2][fn] = __builtin_amdgcn_mfma_f32_16x16x32_bf16(aR[SL][2], bs[SB][fn], acc[2][fn], 0, 0, 0); \
    acc[3][fn] = __builtin_amdgcn_mfma_f32_16x16x32_bf16(aR[SL][3], bs[SB][fn], acc[3][fn], 0, 0, 0); \
    acc[4][fn] = __builtin_amdgcn_mfma_f32_16x16x32_bf16(aR[SL][4], bs[SB][fn], acc[4][fn], 0, 0, 0); \
  }                                                                            \
  __builtin_amdgcn_s_setprio(0);

  // ---- phase A staging: granules 0..27, 2352 chunks (9 rounds + 48) ----
#pragma unroll
  for (int ri = 0; ri < 9; ++ri) {
    const int d = ri * 256 + tid;
    const int g = d / EROWS, prow = d - g * EROWS;
    const int bb = prow / 42, sp = prow - bb * 42;
    const int tok = (sp == 0 || sp == 41) ? VOCAB : x[(b0 + bb) * SEQ + sp - 1];
    gload_lds16(smem + d * 16, Wb + (size_t)tok * PCOL + g * 8);
  }
  if (tid < 48) {
    const int d = 2304 + tid;
    const int g = d / EROWS, prow = d - g * EROWS;
    const int bb = prow / 42, sp = prow - bb * 42;
    const int tok = (sp == 0 || sp == 41) ? VOCAB : x[(b0 + bb) * SEQ + sp - 1];
    gload_lds16(smem + d * 16, Wb + (size_t)tok * PCOL + g * 8);
  }
  LOADB(0, 0)                                       // T(0)=0
  LOADB(1, 1)                                       // T(1)=1
  __syncthreads();                                  // phase-A tile + B(0,1) resident

  // ---- phase A: 21 steps, s -> (kh=s/7, kq=s%7), B tile = kh*10+kq, A quad = kq ----
  LOADA(0, 0, 0)
#pragma unroll
  for (int s = 0; s < 21; ++s) {
    if (s + 1 < 21) { LOADA((s + 1) & 1, (s + 1) % 7, (s + 1) / 7) }
    if (s + 2 < 21) { const int n = s + 2; LOADB(n % 3, (n / 7) * 10 + (n % 7)) }
    MFMAS(s & 1, s % 3)
  }

  __syncthreads();                                  // all phase-A LDS reads done

  // ---- phase B restage: granules 28..39 -> slots 0..11, 1008 chunks (3 rounds + 240) ----
#pragma unroll
  for (int ri = 0; ri < 3; ++ri) {
    const int d = ri * 256 + tid;
    const int g = d / EROWS, prow = d - g * EROWS;
    const int bb = prow / 42, sp = prow - bb * 42;
    const int tok = (sp == 0 || sp == 41) ? VOCAB : x[(b0 + bb) * SEQ + sp - 1];
    gload_lds16(smem + d * 16, Wb + (size_t)tok * PCOL + (GSLOT + g) * 8);
  }
  if (tid < 240) {
    const int d = 768 + tid;
    const int g = d / EROWS, prow = d - g * EROWS;
    const int bb = prow / 42, sp = prow - bb * 42;
    const int tok = (sp == 0 || sp == 41) ? VOCAB : x[(b0 + bb) * SEQ + sp - 1];
    gload_lds16(smem + d * 16, Wb + (size_t)tok * PCOL + (GSLOT + g) * 8);
  }
  LOADB(0, 7)                                       // TB(0) = 7
  LOADB(1, 8)                                       // TB(1) = 8
  __syncthreads();                                  // phase-B tile + B(7,8) resident

  // ---- phase B: 9 steps, s -> (kh=s/3, kq=7+s%3), B tile = kh*10+kq, A quad = s%3 ----
  LOADA(0, 0, 0)
#pragma unroll
  for (int s = 0; s < 9; ++s) {
    if (s + 1 < 9) { LOADA((s + 1) & 1, (s + 1) % 3, (s + 1) / 3) }
    if (s + 2 < 9) { const int n = s + 2; LOADB(n % 3, (n / 3) * 10 + 7 + (n % 3)) }
    MFMAS(s & 1, s % 3)
  }
#undef LOADA
#undef LOADB
#undef MFMAS

  __syncthreads();                                  // phase-B reads done -> act alias safe

  // ---- epilogue: 5 chunks of 16 rows (one per fm); bias+relu -> LDS -> channel-group max ----
#pragma unroll
  for (int fm = 0; fm < 5; ++fm) {
#pragma unroll
    for (int fn = 0; fn < 3; ++fn) {
      const int col = wc * 48 + fn * 16 + l15;      // < 192 < 210
      const float bias = convb[col];
#pragma unroll
      for (int rg = 0; rg < 4; ++rg) {
        const int rloc = l4 * 4 + rg;               // 0..15 within chunk
        float vv = acc[fm][fn][rg] + bias;
        act[rloc * ASTR + col] = fmaxf(vv, 0.f);
      }
    }
    __syncthreads();
    if (tid < 80) {                                 // 16 rows x 5 groups
      const int rl = tid / 5, gq = tid - rl * 5;
      const float* ap = act + rl * ASTR + gq * KPOOL;
      float mx = 0.f;                               // relu => values >= 0
#pragma unroll
      for (int i = 0; i < KPOOL; ++i) mx = fmaxf(mx, ap[i]);
      const int mloc = fm * 16 + rl;
      const int bb = (mloc >= 40) ? 1 : 0;
      const int ss = mloc - 40 * bb;
      maxc[((b0 + bb) * NBLK + gq) * SEQ + ss] = mx; // unmasked max; mask applied in k_dense
    }
    __syncthreads();
  }
}

// ---- kernel 4: region-masked dense (120->35) + out (35->35) ----
__global__ __launch_bounds__(256) void k_dense(const float* __restrict__ maxc,
                                               const int* __restrict__ pos,
                                               const float* __restrict__ dw,
                                               const float* __restrict__ db,
                                               const float* __restrict__ ow,
                                               const float* __restrict__ ob,
                                               float* __restrict__ out) {
  __shared__ float dwL[120 * 36];
  __shared__ float owL[35 * 36];
  __shared__ float hL[64 * 36];
  __shared__ float mxL[64 * 40];
  const int tid = threadIdx.x;
  const int r0 = blockIdx.x * 64;                    // 640 blocks x 64 rows
  for (int i = tid; i < 120 * 35; i += 256) { int j = i / 35, d = i - j * 35; dwL[j * 36 + d] = dw[i]; }
  for (int i = tid; i < 35 * 35; i += 256)  { int j = i / 35, d = i - j * 35; owL[j * 36 + d] = ow[i]; }
  for (int i = tid; i < 64 * 40; i += 256)  mxL[i] = maxc[(size_t)r0 * 40 + i];
  __syncthreads();
  for (int t = tid; t < 64 * 35; t += 256) {
    const int row = t / 35, d = t - row * 35;
    const int rg = r0 + row;
    const int b = rg / NBLK;
    const int p0 = pos[b * 2], p1 = pos[b * 2 + 1];
    int e1 = min(p0, p1), e2 = max(p0, p1);
    if (e1 == 0) { e1 = 1; e2 += 1; }
    float a = db[d];
#pragma unroll
    for (int s = 0; s < SEQ; ++s) {
      const int k = (s >= e1) + (s >= e2);           // region of position s
      a += mxL[row * 40 + s] * dwL[(k * SEQ + s) * 36 + d];
    }
    hL[row * 36 + d] = a;
  }
  __syncthreads();
  for (int t = tid; t < 64 * 35; t += 256) {
    const int row = t / 35, c = t - row * 35;
    float a = ob[c];
#pragma unroll
    for (int d = 0; d < DH; ++d) a += hL[row * 36 + d] * owL[d * 36 + c];
    out[(size_t)(r0 + row) * NCLS + c] = a;
  }
}

extern "C" void kernel_launch(void* const* d_in, const int* in_sizes, int n_in,
                              void* d_out, int out_size, void* d_ws, size_t ws_size,
                              hipStream_t stream) {
  const int*   x     = (const int*)d_in[0];
  const int*   pos   = (const int*)d_in[1];
  const float* w2v   = (const float*)d_in[2];
  const float* convw = (const float*)d_in[3];
  const float* convb = (const float*)d_in[4];
  const float* dw    = (const float*)d_in[5];
  const float* db    = (const float*)d_in[6];
  const float* ow    = (const float*)d_in[7];
  const float* ob    = (const float*)d_in[8];
  float* out = (float*)d_out;

  char* ws = (char*)d_ws;
  u16* W    = (u16*)ws;                               // (100001)*320*2 = 64,000,640 B
  u16* Btn  = (u16*)(ws + 64000640);                  // 120*192*8*2   =    368,640 B
  float* maxc = (float*)(ws + 64000640 + 368640);     // 40960*40*4    =  6,553,600 B

  k_prepW<<<15626, 256, 0, stream>>>(w2v, W);         // (100001*40+255)/256
  k_prepB<<<90, 256, 0, stream>>>(convw, Btn);        // 23040/256
  k_conv_gemm<<<4096, 256, 0, stream>>>(W, Btn, x, convb, maxc);  // 327680/80
  k_dense<<<640, 256, 0, stream>>>(maxc, pos, dw, db, ow, ob, out);
}